// Round 2
// baseline (219.488 us; speedup 1.0000x reference)
//
#include <hip/hip_runtime.h>

// Problem constants
#define B 8
#define S 4096
#define H 32
#define D 128
#define DM 4096   // H*D

#define SPLIT 4
#define SC (S / SPLIT)    // 1024 s-rows per block
#define NT 512
#define NWAVE 8           // NT/64
#define PSTR 132          // partial record stride (floats): 128 O + m + l (+pad)

// ---------------------------------------------------------------------------
// Kernel 1: q = hidden @ Wq^T + bq.  1024 blocks x 256 thr; one wave per
// output column j (all 8 batches). Wq rows read exactly once, coalesced
// float4; hidden (128 KB) is L1/L2-resident.
// ---------------------------------------------------------------------------
__global__ __launch_bounds__(256) void qproj_kernel(
    const float* __restrict__ hidden, const float* __restrict__ Wq,
    const float* __restrict__ bq, float* __restrict__ qout)
{
    const int lane = threadIdx.x & 63;
    const int wave = threadIdx.x >> 6;
    const int j = blockIdx.x * 4 + wave;

    const float4* __restrict__ w   = (const float4*)(Wq + (size_t)j * DM);
    const float4* __restrict__ hid = (const float4*)hidden;

    float a[B];
#pragma unroll
    for (int b = 0; b < B; ++b) a[b] = 0.f;

#pragma unroll 4
    for (int i = 0; i < DM / (4 * 64); ++i) {   // 16 iterations
        const int idx = lane + 64 * i;
        const float4 wv = w[idx];
#pragma unroll
        for (int b = 0; b < B; ++b) {
            const float4 hv = hid[b * (DM / 4) + idx];
            a[b] += wv.x * hv.x + wv.y * hv.y + wv.z * hv.z + wv.w * hv.w;
        }
    }
#pragma unroll
    for (int b = 0; b < B; ++b) {
#pragma unroll
        for (int mk = 1; mk <= 32; mk <<= 1) a[b] += __shfl_xor(a[b], mk);
    }
    if (lane == 0) {
        const float bias = bq[j];
#pragma unroll
        for (int b = 0; b < B; ++b) qout[b * DM + j] = a[b] + bias;
    }
}

// ---------------------------------------------------------------------------
// Kernel 2: flash-decode partial. One block per (b,h,chunk): 1024 s-rows.
// 512 thr = 8 waves = 16 32-lane groups. Chunk-local stable softmax;
// writes partial O[128], m, l to workspace.
// ---------------------------------------------------------------------------
__global__ __launch_bounds__(NT) void attn_partial(
    const float* __restrict__ kptr, const float* __restrict__ vptr,
    const float* __restrict__ qws, float* __restrict__ part)
{
    __shared__ float sc[SC];            // 4 KB
    __shared__ float red[NWAVE];
    __shared__ float outp[NWAVE][D];    // 4 KB

    const int tid  = threadIdx.x;
    const int lane = tid & 63;
    const int wave = tid >> 6;
    const int gid  = tid >> 5;          // 0..15
    const int g    = lane >> 5;
    const int l    = lane & 31;
    const int c    = blockIdx.x & (SPLIT - 1);
    const int h    = (blockIdx.x >> 2) & (H - 1);
    const int b    = blockIdx.x >> 7;

    // element offset of (b, s = c*SC, h, d = 0)
    const size_t base = (((size_t)b * S + (size_t)c * SC) * H + h) * D;
    const float* kb = kptr + base;
    const float* vb = vptr + base;

    const float4 q4 = *(const float4*)(qws + (size_t)b * DM + h * D + 4 * l);

    // ---- Phase 1: scores for this chunk ----
#pragma unroll 4
    for (int it = 0; it < SC / 16; ++it) {          // 64 iterations
        const int s = it * 16 + gid;
        const float4 k4 = *(const float4*)(kb + (size_t)s * DM + 4 * l);
        float p = q4.x * k4.x + q4.y * k4.y + q4.z * k4.z + q4.w * k4.w;
        p += __shfl_xor(p, 16);
        p += __shfl_xor(p, 8);
        p += __shfl_xor(p, 4);
        p += __shfl_xor(p, 2);
        p += __shfl_xor(p, 1);
        if (l == 0) sc[s] = p;
    }
    __syncthreads();

    // ---- chunk max ----
    float m = -3.4e38f;
#pragma unroll
    for (int i = tid; i < SC; i += NT) m = fmaxf(m, sc[i]);
#pragma unroll
    for (int mk = 1; mk <= 32; mk <<= 1) m = fmaxf(m, __shfl_xor(m, mk));
    if (lane == 0) red[wave] = m;
    __syncthreads();
    float M = red[0];
#pragma unroll
    for (int w = 1; w < NWAVE; ++w) M = fmaxf(M, red[w]);

    // ---- exp + chunk sum (unnormalized exp kept in sc) ----
    float lsum = 0.f;
#pragma unroll
    for (int i = tid; i < SC; i += NT) {
        const float e = __expf(sc[i] - M);
        sc[i] = e;
        lsum += e;
    }
#pragma unroll
    for (int mk = 1; mk <= 32; mk <<= 1) lsum += __shfl_xor(lsum, mk);
    __syncthreads();                    // red max-reads + sc writes complete
    if (lane == 0) red[wave] = lsum;
    __syncthreads();
    float tot = 0.f;
#pragma unroll
    for (int w = 0; w < NWAVE; ++w) tot += red[w];

    // ---- Phase 2: partial O = exp(S) @ V ----
    float4 acc = make_float4(0.f, 0.f, 0.f, 0.f);
    const int s0 = wave * (SC / NWAVE); // 128 contiguous s per wave
#pragma unroll 4
    for (int i = 0; i < SC / NWAVE; i += 2) {       // 64 iterations
        const int s = s0 + i + g;
        const float p = sc[s];
        const float4 v4 = *(const float4*)(vb + (size_t)s * DM + 4 * l);
        acc.x += p * v4.x;
        acc.y += p * v4.y;
        acc.z += p * v4.z;
        acc.w += p * v4.w;
    }
    acc.x += __shfl_xor(acc.x, 32);
    acc.y += __shfl_xor(acc.y, 32);
    acc.z += __shfl_xor(acc.z, 32);
    acc.w += __shfl_xor(acc.w, 32);
    if (g == 0) *(float4*)(&outp[wave][4 * l]) = acc;
    __syncthreads();

    // ---- write partial record ----
    float* rec = part + ((size_t)(b * H + h) * SPLIT + c) * PSTR;
    if (tid < D) {
        float r = 0.f;
#pragma unroll
        for (int w = 0; w < NWAVE; ++w) r += outp[w][tid];
        rec[tid] = r;
    } else if (tid == D) {
        rec[D] = M;
        rec[D + 1] = tot;
    }
}

// ---------------------------------------------------------------------------
// Kernel 3: merge the SPLIT partials per (b,h).
// ---------------------------------------------------------------------------
__global__ __launch_bounds__(128) void combine_kernel(
    const float* __restrict__ part, float* __restrict__ out)
{
    const int bh = blockIdx.x;          // 0..255
    const int d  = threadIdx.x;         // 0..127
    const float* rec = part + (size_t)bh * SPLIT * PSTR;

    float M = -3.4e38f;
#pragma unroll
    for (int c = 0; c < SPLIT; ++c) M = fmaxf(M, rec[c * PSTR + D]);
    float denom = 0.f, o = 0.f;
#pragma unroll
    for (int c = 0; c < SPLIT; ++c) {
        const float w = __expf(rec[c * PSTR + D] - M);
        denom += w * rec[c * PSTR + D + 1];
        o     += w * rec[c * PSTR + d];
    }
    out[(size_t)bh * D + d] = o / denom;
}

extern "C" void kernel_launch(void* const* d_in, const int* in_sizes, int n_in,
                              void* d_out, int out_size, void* d_ws, size_t ws_size,
                              hipStream_t stream)
{
    const float* hidden = (const float*)d_in[0];
    const float* keys   = (const float*)d_in[1];
    const float* vals   = (const float*)d_in[2];
    const float* Wq     = (const float*)d_in[3];
    const float* bq     = (const float*)d_in[4];
    float* outp = (float*)d_out;
    float* qws  = (float*)d_ws;                   // B*DM floats = 128 KB
    float* part = qws + (size_t)B * DM;           // 256*4*132 floats ≈ 528 KB

    qproj_kernel<<<DM / 4, 256, 0, stream>>>(hidden, Wq, bq, qws);
    attn_partial<<<B * H * SPLIT, NT, 0, stream>>>(keys, vals, qws, part);
    combine_kernel<<<B * H, 128, 0, stream>>>(part, outp);
}